// Round 1
// baseline (260.343 us; speedup 1.0000x reference)
//
#include <hip/hip_runtime.h>

// Problem constants (from reference)
#define CCH   640       // channels
#define WIN   19        // input spatial width
#define NWp   5         // pooled width
#define P     25        // NW*NW
#define BSn   100       // B*S = 20*5
#define BSC   64000     // BSn*CCH
#define META_ELEMS 3200000  // 100 * 1280 * 25

// Kernel 1: adaptive avg pool 19x19 -> 5x5 for both tensors, writing the
// meta_input region of d_out ([B,S,2C,5,5], support at ch [0,640), query at
// [640,1280)). One wave per slice; 4 waves (slices) per block.
__global__ __launch_bounds__(256) void pool_kernel(
    const float* __restrict__ sup, const float* __restrict__ qry,
    float* __restrict__ out) {
  __shared__ float tile[4][WIN * WIN];
  const int wave = threadIdx.x >> 6;
  const int lane = threadIdx.x & 63;
  const int slice = blockIdx.x * 4 + wave;           // [0, 2*BSC)
  const int which = slice >= BSC ? 1 : 0;
  const int rem = which ? slice - BSC : slice;       // [0, BSC)
  const float* __restrict__ src =
      (which ? qry : sup) + (size_t)rem * (WIN * WIN);

  for (int k = lane; k < WIN * WIN; k += 64) tile[wave][k] = src[k];
  __syncthreads();

  if (lane < P) {
    const int i = lane / NWp, j = lane % NWp;
    const int r0 = (i * WIN) / NWp, r1 = ((i + 1) * WIN + NWp - 1) / NWp;
    const int c0 = (j * WIN) / NWp, c1 = ((j + 1) * WIN + NWp - 1) / NWp;
    float sum = 0.f;
    for (int r = r0; r < r1; ++r)
      for (int c = c0; c < c1; ++c)
        sum += tile[wave][r * WIN + c];
    const float inv = 1.0f / (float)((r1 - r0) * (c1 - c0));
    const int bs = rem / CCH;
    const int c  = rem % CCH;
    out[((size_t)bs * (2 * CCH) + which * CCH + c) * P + lane] = sum * inv;
  }
}

// Kernel 2: all-pairs cosine similarity over channels + max over query pos.
// One block per (b,s). Reads pooled data back from the meta region of d_out.
__global__ __launch_bounds__(640) void cos_kernel(
    const float* __restrict__ meta, float* __restrict__ out) {
  constexpr int CHUNK = 128;            // channels per LDS stage (640/128 = 5)
  __shared__ float ls[CHUNK * P];
  __shared__ float lq[CHUNK * P];
  __shared__ float sn2[P], qn2[P];
  __shared__ float simbuf[P * P];

  const int t  = threadIdx.x;
  const int bs = blockIdx.x;
  const float* __restrict__ sbase = meta + (size_t)bs * (2 * CCH) * P;
  const float* __restrict__ qbase = sbase + (size_t)CCH * P;

  const int p = t / P;
  const int q = t - p * P;
  float dot = 0.f;
  float nrm = 0.f;

  for (int ch = 0; ch < CCH / CHUNK; ++ch) {
    __syncthreads();   // previous chunk's consumers done before overwrite
    const int off = ch * CHUNK * P;
    for (int k = t; k < CHUNK * P; k += 640) {
      ls[k] = sbase[off + k];
      lq[k] = qbase[off + k];
    }
    __syncthreads();

    if (t < P * P) {
#pragma unroll 8
      for (int k = 0; k < CHUNK; ++k)
        dot = fmaf(ls[k * P + p], lq[k * P + q], dot);
    }
    if (t < P) {
#pragma unroll 8
      for (int k = 0; k < CHUNK; ++k) {
        float v = ls[k * P + t];
        nrm = fmaf(v, v, nrm);
      }
    } else if (t >= 32 && t < 32 + P) {
      const int qq = t - 32;
#pragma unroll 8
      for (int k = 0; k < CHUNK; ++k) {
        float v = lq[k * P + qq];
        nrm = fmaf(v, v, nrm);
      }
    }
  }

  if (t < P) sn2[t] = nrm;
  if (t >= 32 && t < 32 + P) qn2[t - 32] = nrm;
  __syncthreads();

  if (t < P * P) {
    const float denom = fmaxf(sqrtf(sn2[p]) * sqrtf(qn2[q]), 1e-8f);
    simbuf[t] = dot / denom;
  }
  __syncthreads();

  if (t < P) {
    float m = simbuf[t * P];
#pragma unroll
    for (int k = 1; k < P; ++k) m = fmaxf(m, simbuf[t * P + k]);
    out[META_ELEMS + (size_t)bs * P + t] = m;
  }
}

extern "C" void kernel_launch(void* const* d_in, const int* in_sizes, int n_in,
                              void* d_out, int out_size, void* d_ws, size_t ws_size,
                              hipStream_t stream) {
  const float* sup = (const float*)d_in[0];
  const float* qry = (const float*)d_in[1];
  float* out = (float*)d_out;

  // 2 * BSC slices, 4 per block
  pool_kernel<<<(2 * BSC) / 4, 256, 0, stream>>>(sup, qry, out);
  cos_kernel<<<BSn, 640, 0, stream>>>(out, out);
}

// Round 2
// 219.142 us; speedup vs baseline: 1.1880x; 1.1880x over previous
//
#include <hip/hip_runtime.h>

// Problem constants
#define CCH   640        // channels
#define WIN   19         // input spatial width
#define NWp   5          // pooled width
#define P     25         // NW*NW
#define BSn   100        // B*S
#define BSC   64000      // BSn*CCH slices per tensor
#define META_ELEMS 3200000
#define SLICES_PER_BLK 16
#define SLICE_F (WIN*WIN)            // 361
#define GRP_F  (SLICES_PER_BLK*SLICE_F)  // 5776 floats, 23104 B (16B-aligned)
#define NGRP_PER_TENSOR (BSC / SLICES_PER_BLK)   // 4000

// ---------------------------------------------------------------------------
// Kernel 1: adaptive avg pool 19x19 -> 5x5, both tensors, writes meta region.
// Block = 256 threads handles 16 consecutive slices: bulk float4 load to LDS
// (group is 16B-aligned), one barrier, 400 bin outputs with all lanes active.
// ---------------------------------------------------------------------------
__global__ __launch_bounds__(256) void pool_kernel(
    const float* __restrict__ sup, const float* __restrict__ qry,
    float* __restrict__ out) {
  __shared__ float tile[GRP_F];
  const int g   = blockIdx.x;               // [0, 8000)
  const int tid = threadIdx.x;
  const int which = (g >= NGRP_PER_TENSOR) ? 1 : 0;
  const int gl = which ? g - NGRP_PER_TENSOR : g;
  const float* __restrict__ src = (which ? qry : sup) + (size_t)gl * GRP_F;

  // Bulk coalesced load: 5776 floats = 1444 float4
  float4* __restrict__ t4 = (float4*)tile;
  const float4* __restrict__ s4 = (const float4*)src;
  for (int k = tid; k < GRP_F / 4; k += 256) t4[k] = s4[k];
  __syncthreads();

  const int slice0 = gl * SLICES_PER_BLK;   // slice idx within tensor
  for (int o = tid; o < SLICES_PER_BLK * P; o += 256) {
    const int s = o / P, p = o - s * P;
    const int i = p / NWp, j = p - i * NWp;
    const int r0 = (i * WIN) / NWp, r1 = ((i + 1) * WIN + NWp - 1) / NWp;
    const int c0 = (j * WIN) / NWp, c1 = ((j + 1) * WIN + NWp - 1) / NWp;
    const float* __restrict__ tb = tile + s * SLICE_F;
    float sum = 0.f;
    for (int r = r0; r < r1; ++r)
#pragma unroll
      for (int c = 0; c < 5; ++c) {           // max bin width is 5
        if (c0 + c < c1) sum += tb[r * WIN + c0 + c];
      }
    const float val = sum / (float)((r1 - r0) * (c1 - c0));
    const int rem = slice0 + s;
    const int bs = rem / CCH, cch = rem - bs * CCH;
    out[((size_t)bs * (2 * CCH) + which * CCH + cch) * P + p] = val;
  }
}

// ---------------------------------------------------------------------------
// Kernel 2a: partial dots/norms per (bs, 128-channel chunk). 500 blocks.
// ---------------------------------------------------------------------------
#define CHUNK 128
__global__ __launch_bounds__(640) void cos_part(
    const float* __restrict__ meta, float* __restrict__ dpart,
    float* __restrict__ spart, float* __restrict__ qpart) {
  __shared__ float ls[CHUNK * P];
  __shared__ float lq[CHUNK * P];
  const int t   = threadIdx.x;
  const int blk = blockIdx.x;              // bs*5 + ch
  const int bs  = blk / 5, ch = blk - bs * 5;
  const float* __restrict__ sb = meta + (size_t)bs * (2 * CCH * P) + ch * (CHUNK * P);
  const float* __restrict__ qb = sb + CCH * P;

  float4* __restrict__ ls4 = (float4*)ls;
  float4* __restrict__ lq4 = (float4*)lq;
  const float4* __restrict__ sb4 = (const float4*)sb;
  const float4* __restrict__ qb4 = (const float4*)qb;
  for (int k = t; k < (CHUNK * P) / 4; k += 640) {
    ls4[k] = sb4[k];
    lq4[k] = qb4[k];
  }
  __syncthreads();

  if (t < P * P) {
    const int p = t / P, q = t - p * P;
    float dot = 0.f;
#pragma unroll 8
    for (int k = 0; k < CHUNK; ++k)
      dot = fmaf(ls[k * P + p], lq[k * P + q], dot);
    dpart[(size_t)blk * (P * P) + t] = dot;
  }
  if (t < P) {
    float n = 0.f;
#pragma unroll 8
    for (int k = 0; k < CHUNK; ++k) { float v = ls[k * P + t]; n = fmaf(v, v, n); }
    spart[blk * P + t] = n;
  } else if (t >= 32 && t < 32 + P) {
    const int q = t - 32;
    float n = 0.f;
#pragma unroll 8
    for (int k = 0; k < CHUNK; ++k) { float v = lq[k * P + q]; n = fmaf(v, v, n); }
    qpart[blk * P + q] = n;
  }
}

// ---------------------------------------------------------------------------
// Kernel 2b: reduce 5 partials, normalize, max over query positions.
// ---------------------------------------------------------------------------
__global__ __launch_bounds__(640) void cos_final(
    const float* __restrict__ dpart, const float* __restrict__ spart,
    const float* __restrict__ qpart, float* __restrict__ out) {
  __shared__ float sn[P], qn[P], simbuf[P * P];
  const int t = threadIdx.x, bs = blockIdx.x;
  if (t < P) {
    float a = 0.f;
#pragma unroll
    for (int ch = 0; ch < 5; ++ch) a += spart[(bs * 5 + ch) * P + t];
    sn[t] = sqrtf(a);
  } else if (t >= 32 && t < 32 + P) {
    const int q = t - 32;
    float a = 0.f;
#pragma unroll
    for (int ch = 0; ch < 5; ++ch) a += qpart[(bs * 5 + ch) * P + q];
    qn[q] = sqrtf(a);
  }
  __syncthreads();
  if (t < P * P) {
    const int p = t / P, q = t - p * P;
    float d = 0.f;
#pragma unroll
    for (int ch = 0; ch < 5; ++ch) d += dpart[(size_t)(bs * 5 + ch) * (P * P) + t];
    simbuf[t] = d / fmaxf(sn[p] * qn[q], 1e-8f);
  }
  __syncthreads();
  if (t < P) {
    float m = simbuf[t * P];
#pragma unroll
    for (int k = 1; k < P; ++k) m = fmaxf(m, simbuf[t * P + k]);
    out[META_ELEMS + bs * P + t] = m;
  }
}

extern "C" void kernel_launch(void* const* d_in, const int* in_sizes, int n_in,
                              void* d_out, int out_size, void* d_ws, size_t ws_size,
                              hipStream_t stream) {
  const float* sup = (const float*)d_in[0];
  const float* qry = (const float*)d_in[1];
  float* out = (float*)d_out;

  // Workspace layout (floats): dpart[500*625], spart[500*25], qpart[500*25]
  float* dpart = (float*)d_ws;
  float* spart = dpart + 500 * (P * P);
  float* qpart = spart + 500 * P;

  pool_kernel<<<2 * NGRP_PER_TENSOR, 256, 0, stream>>>(sup, qry, out);
  cos_part<<<BSn * 5, 640, 0, stream>>>(out, dpart, spart, qpart);
  cos_final<<<BSn, 640, 0, stream>>>(dpart, spart, qpart, out);
}

// Round 3
// 215.068 us; speedup vs baseline: 1.2105x; 1.0189x over previous
//
#include <hip/hip_runtime.h>

// Problem constants
#define CCH   640        // channels
#define WIN   19         // input spatial width
#define NWp   5          // pooled width
#define P     25         // NW*NW
#define BSn   100        // B*S
#define BSC   64000      // BSn*CCH slices per tensor
#define META_ELEMS 3200000
#define SLICES_PER_BLK 16
#define SLICE_F (WIN*WIN)                 // 361
#define GRP_F  (SLICES_PER_BLK*SLICE_F)   // 5776 floats (23104 B, 16B-aligned)
#define NGRP_PER_TENSOR (BSC / SLICES_PER_BLK)   // 4000
#define GRP_INSTS 23                      // ceil(5776 / 256) 1KB-per-wave DMA insts

// Async global->LDS DMA, 16 B per lane. Dest is wave-uniform base + lane*16.
__device__ __forceinline__ void gload16(const float* g, float* l) {
  __builtin_amdgcn_global_load_lds(
      (const __attribute__((address_space(1))) void*)g,
      (__attribute__((address_space(3))) void*)l, 16, 0, 0);
}

// ---------------------------------------------------------------------------
// Kernel 1: adaptive avg pool 19x19 -> 5x5, both tensors, writes meta region.
// 16 slices per 256-thread block; staging via global_load_lds (no VGPR
// round-trip, single latency exposure); 400 bin outputs per block.
// ---------------------------------------------------------------------------
__global__ __launch_bounds__(256) void pool_kernel(
    const float* __restrict__ sup, const float* __restrict__ qry,
    float* __restrict__ out) {
  __shared__ __align__(16) float tile[GRP_F];
  const int tid = threadIdx.x;
  const int lane = tid & 63, wave = tid >> 6;
  const int g = blockIdx.x;               // [0, 8000)
  const int which = (g >= NGRP_PER_TENSOR) ? 1 : 0;
  const int gl = which ? g - NGRP_PER_TENSOR : g;
  const float* __restrict__ src = (which ? qry : sup) + (size_t)gl * GRP_F;

  // 23 DMA instructions of 1 KB each (last one: 36 lanes active).
  for (int i = wave; i < GRP_INSTS; i += 4) {
    const int f = i * 256 + lane * 4;     // float index of this lane's 16 B
    if (f < GRP_F) gload16(src + f, tile + i * 256);
  }
  __syncthreads();                        // drains vmcnt, one latency exposure

  const int slice0 = gl * SLICES_PER_BLK;
  for (int o = tid; o < SLICES_PER_BLK * P; o += 256) {
    const int s = o / P, p = o - s * P;
    const int i = p / NWp, j = p - i * NWp;
    const int r0 = (i * WIN) / NWp, r1 = ((i + 1) * WIN + NWp - 1) / NWp;
    const int c0 = (j * WIN) / NWp, c1 = ((j + 1) * WIN + NWp - 1) / NWp;
    const float* __restrict__ tb = tile + s * SLICE_F;
    float sum = 0.f;
    for (int r = r0; r < r1; ++r)
#pragma unroll
      for (int c = 0; c < 5; ++c) {       // max bin width is 5
        if (c0 + c < c1) sum += tb[r * WIN + c0 + c];
      }
    const float val = sum / (float)((r1 - r0) * (c1 - c0));
    const int rem = slice0 + s;
    const int bs = rem / CCH, cch = rem - bs * CCH;
    out[((size_t)bs * (2 * CCH) + which * CCH + cch) * P + p] = val;
  }
}

// ---------------------------------------------------------------------------
// Kernel 2a: partial dots/norms per (bs, 128-channel chunk). 500 blocks.
// ---------------------------------------------------------------------------
#define CHUNK 128
#define CP_FLOATS (CHUNK * P)             // 3200 floats per buffer
#define CP_INSTS  13                      // ceil(3200 / 256)
__global__ __launch_bounds__(640) void cos_part(
    const float* __restrict__ meta, float* __restrict__ dpart,
    float* __restrict__ spart, float* __restrict__ qpart) {
  __shared__ __align__(16) float ls[CP_FLOATS];
  __shared__ __align__(16) float lq[CP_FLOATS];
  const int t = threadIdx.x;
  const int lane = t & 63, wave = t >> 6;  // 10 waves
  const int blk = blockIdx.x;              // bs*5 + ch
  const int bs = blk / 5, ch = blk - bs * 5;
  const float* __restrict__ sb = meta + (size_t)bs * (2 * CCH * P) + ch * CP_FLOATS;
  const float* __restrict__ qb = sb + CCH * P;

  // 26 DMA insts (13 per buffer) spread over 10 waves.
  for (int i = wave; i < 2 * CP_INSTS; i += 10) {
    const int isq = (i >= CP_INSTS);
    const int ii = isq ? i - CP_INSTS : i;
    const int f = ii * 256 + lane * 4;
    if (f < CP_FLOATS)
      gload16((isq ? qb : sb) + f, (isq ? lq : ls) + ii * 256);
  }
  __syncthreads();

  if (t < P * P) {
    const int p = t / P, q = t - p * P;
    float dot = 0.f;
#pragma unroll 8
    for (int k = 0; k < CHUNK; ++k)
      dot = fmaf(ls[k * P + p], lq[k * P + q], dot);
    dpart[(size_t)blk * (P * P) + t] = dot;
  }
  if (t < P) {
    float n = 0.f;
#pragma unroll 8
    for (int k = 0; k < CHUNK; ++k) { float v = ls[k * P + t]; n = fmaf(v, v, n); }
    spart[blk * P + t] = n;
  } else if (t >= 32 && t < 32 + P) {
    const int q = t - 32;
    float n = 0.f;
#pragma unroll 8
    for (int k = 0; k < CHUNK; ++k) { float v = lq[k * P + q]; n = fmaf(v, v, n); }
    qpart[blk * P + q] = n;
  }
}

// ---------------------------------------------------------------------------
// Kernel 2b: reduce 5 partials, normalize, max over query positions.
// ---------------------------------------------------------------------------
__global__ __launch_bounds__(640) void cos_final(
    const float* __restrict__ dpart, const float* __restrict__ spart,
    const float* __restrict__ qpart, float* __restrict__ out) {
  __shared__ float sn[P], qn[P], simbuf[P * P];
  const int t = threadIdx.x, bs = blockIdx.x;
  if (t < P) {
    float a = 0.f;
#pragma unroll
    for (int ch = 0; ch < 5; ++ch) a += spart[(bs * 5 + ch) * P + t];
    sn[t] = sqrtf(a);
  } else if (t >= 32 && t < 32 + P) {
    const int q = t - 32;
    float a = 0.f;
#pragma unroll
    for (int ch = 0; ch < 5; ++ch) a += qpart[(bs * 5 + ch) * P + q];
    qn[q] = sqrtf(a);
  }
  __syncthreads();
  if (t < P * P) {
    const int p = t / P, q = t - p * P;
    float d = 0.f;
#pragma unroll
    for (int ch = 0; ch < 5; ++ch) d += dpart[(size_t)(bs * 5 + ch) * (P * P) + t];
    simbuf[t] = d / fmaxf(sn[p] * qn[q], 1e-8f);
  }
  __syncthreads();
  if (t < P) {
    float m = simbuf[t * P];
#pragma unroll
    for (int k = 1; k < P; ++k) m = fmaxf(m, simbuf[t * P + k]);
    out[META_ELEMS + bs * P + t] = m;
  }
}

extern "C" void kernel_launch(void* const* d_in, const int* in_sizes, int n_in,
                              void* d_out, int out_size, void* d_ws, size_t ws_size,
                              hipStream_t stream) {
  const float* sup = (const float*)d_in[0];
  const float* qry = (const float*)d_in[1];
  float* out = (float*)d_out;

  // Workspace layout (floats): dpart[500*625], spart[500*25], qpart[500*25]
  float* dpart = (float*)d_ws;
  float* spart = dpart + 500 * (P * P);
  float* qpart = spart + 500 * P;

  pool_kernel<<<2 * NGRP_PER_TENSOR, 256, 0, stream>>>(sup, qry, out);
  cos_part<<<BSn * 5, 640, 0, stream>>>(out, dpart, spart, qpart);
  cos_final<<<BSn, 640, 0, stream>>>(dpart, spart, qpart, out);
}

// Round 4
// 213.527 us; speedup vs baseline: 1.2192x; 1.0072x over previous
//
#include <hip/hip_runtime.h>

// Problem constants
#define CCH   640        // channels
#define WIN   19         // input spatial width
#define NWp   5          // pooled width
#define P     25         // NW*NW
#define BSn   100        // B*S
#define BSC   64000      // BSn*CCH slices per tensor
#define META_ELEMS 3200000
#define SLICE_F 361               // 19*19
#define WGRP_SL 4                 // slices per wave (4*361 = 1444 floats = 5776 B, 16B-aligned)
#define WGRP_F  (WGRP_SL * SLICE_F)   // 1444
#define WGRP_V4 361               // float4s per wave-group
#define NWG_PER_TENSOR (BSC / WGRP_SL)   // 16000 wave-groups per tensor

// Async global->LDS DMA, 16 B per lane. Dest = wave-uniform base + lane*16.
__device__ __forceinline__ void gload16(const float* g, float* l) {
  __builtin_amdgcn_global_load_lds(
      (const __attribute__((address_space(1))) void*)g,
      (__attribute__((address_space(3))) void*)l, 16, 0, 0);
}

// ---------------------------------------------------------------------------
// Kernel 1: adaptive avg pool, BARRIER-FREE. Each wave autonomously stages
// its private 4-slice LDS region via global_load_lds, waits only its own
// vmcnt (imm 0x0F70 = vmcnt(0), lgkm/exp no-wait), computes 100 bins, writes.
// No __syncthreads anywhere -> waves de-phase, keeping DMA queue + VALU busy.
// ---------------------------------------------------------------------------
__global__ __launch_bounds__(256) void pool_kernel(
    const float* __restrict__ sup, const float* __restrict__ qry,
    float* __restrict__ out) {
  __shared__ __align__(16) float tile[4 * WGRP_F];   // 23104 B, wave-private quarters
  const int lane = threadIdx.x & 63;
  const int wave = threadIdx.x >> 6;
  const int wg = blockIdx.x * 4 + wave;              // [0, 32000)
  const int which = (wg >= NWG_PER_TENSOR) ? 1 : 0;
  const int g = which ? wg - NWG_PER_TENSOR : wg;
  const float* __restrict__ src = (which ? qry : sup) + (size_t)g * WGRP_F;
  float* __restrict__ lt = tile + wave * WGRP_F;

  // 6 DMA insts (1 KB each; last has 41/64 lanes), back-to-back.
#pragma unroll
  for (int i = 0; i < 6; ++i) {
    const int v = i * 64 + lane;                     // float4 index
    if (v < WGRP_V4) gload16(src + v * 4, lt + i * 256);
  }
  __builtin_amdgcn_wave_barrier();
  __builtin_amdgcn_s_waitcnt(0x0F70);   // wait this wave's vmcnt(0) only
  __builtin_amdgcn_wave_barrier();

  const int slice0 = g * WGRP_SL;                    // slice idx within tensor
  for (int o = lane; o < WGRP_SL * P; o += 64) {     // 100 outputs per wave
    const int s = o / P, p = o - s * P;
    const int i = p / NWp, j = p - i * NWp;
    const int r0 = (i * WIN) / NWp, r1 = ((i + 1) * WIN + NWp - 1) / NWp;
    const int c0 = (j * WIN) / NWp, c1 = ((j + 1) * WIN + NWp - 1) / NWp;
    const float* __restrict__ tb = lt + s * SLICE_F;
    float sum = 0.f;
    for (int r = r0; r < r1; ++r)
#pragma unroll
      for (int c = 0; c < 5; ++c) {                  // max bin width is 5
        if (c0 + c < c1) sum += tb[r * WIN + c0 + c];
      }
    const float val = sum / (float)((r1 - r0) * (c1 - c0));
    const int rem = slice0 + s;
    const int bs = rem / CCH, cch = rem - bs * CCH;
    out[((size_t)bs * (2 * CCH) + which * CCH + cch) * P + p] = val;
  }
}

// ---------------------------------------------------------------------------
// Kernel 2a: partial dots/norms per (bs, 128-channel chunk). 500 blocks.
// ---------------------------------------------------------------------------
#define CHUNK 128
#define CP_FLOATS (CHUNK * P)             // 3200 floats per buffer
#define CP_INSTS  13                      // ceil(3200 / 256)
__global__ __launch_bounds__(640) void cos_part(
    const float* __restrict__ meta, float* __restrict__ dpart,
    float* __restrict__ spart, float* __restrict__ qpart) {
  __shared__ __align__(16) float ls[CP_FLOATS];
  __shared__ __align__(16) float lq[CP_FLOATS];
  const int t = threadIdx.x;
  const int lane = t & 63, wave = t >> 6;  // 10 waves
  const int blk = blockIdx.x;              // bs*5 + ch
  const int bs = blk / 5, ch = blk - bs * 5;
  const float* __restrict__ sb = meta + (size_t)bs * (2 * CCH * P) + ch * CP_FLOATS;
  const float* __restrict__ qb = sb + CCH * P;

  for (int i = wave; i < 2 * CP_INSTS; i += 10) {
    const int isq = (i >= CP_INSTS);
    const int ii = isq ? i - CP_INSTS : i;
    const int f = ii * 256 + lane * 4;
    if (f < CP_FLOATS)
      gload16((isq ? qb : sb) + f, (isq ? lq : ls) + ii * 256);
  }
  __syncthreads();

  if (t < P * P) {
    const int p = t / P, q = t - p * P;
    float dot = 0.f;
#pragma unroll 8
    for (int k = 0; k < CHUNK; ++k)
      dot = fmaf(ls[k * P + p], lq[k * P + q], dot);
    dpart[(size_t)blk * (P * P) + t] = dot;
  }
  if (t < P) {
    float n = 0.f;
#pragma unroll 8
    for (int k = 0; k < CHUNK; ++k) { float v = ls[k * P + t]; n = fmaf(v, v, n); }
    spart[blk * P + t] = n;
  } else if (t >= 32 && t < 32 + P) {
    const int q = t - 32;
    float n = 0.f;
#pragma unroll 8
    for (int k = 0; k < CHUNK; ++k) { float v = lq[k * P + q]; n = fmaf(v, v, n); }
    qpart[blk * P + q] = n;
  }
}

// ---------------------------------------------------------------------------
// Kernel 2b: reduce 5 partials, normalize, max over query positions.
// ---------------------------------------------------------------------------
__global__ __launch_bounds__(640) void cos_final(
    const float* __restrict__ dpart, const float* __restrict__ spart,
    const float* __restrict__ qpart, float* __restrict__ out) {
  __shared__ float sn[P], qn[P], simbuf[P * P];
  const int t = threadIdx.x, bs = blockIdx.x;
  if (t < P) {
    float a = 0.f;
#pragma unroll
    for (int ch = 0; ch < 5; ++ch) a += spart[(bs * 5 + ch) * P + t];
    sn[t] = sqrtf(a);
  } else if (t >= 32 && t < 32 + P) {
    const int q = t - 32;
    float a = 0.f;
#pragma unroll
    for (int ch = 0; ch < 5; ++ch) a += qpart[(bs * 5 + ch) * P + q];
    qn[q] = sqrtf(a);
  }
  __syncthreads();
  if (t < P * P) {
    const int p = t / P, q = t - p * P;
    float d = 0.f;
#pragma unroll
    for (int ch = 0; ch < 5; ++ch) d += dpart[(size_t)(bs * 5 + ch) * (P * P) + t];
    simbuf[t] = d / fmaxf(sn[p] * qn[q], 1e-8f);
  }
  __syncthreads();
  if (t < P) {
    float m = simbuf[t * P];
#pragma unroll
    for (int k = 1; k < P; ++k) m = fmaxf(m, simbuf[t * P + k]);
    out[META_ELEMS + bs * P + t] = m;
  }
}

extern "C" void kernel_launch(void* const* d_in, const int* in_sizes, int n_in,
                              void* d_out, int out_size, void* d_ws, size_t ws_size,
                              hipStream_t stream) {
  const float* sup = (const float*)d_in[0];
  const float* qry = (const float*)d_in[1];
  float* out = (float*)d_out;

  // Workspace layout (floats): dpart[500*625], spart[500*25], qpart[500*25]
  float* dpart = (float*)d_ws;
  float* spart = dpart + 500 * (P * P);
  float* qpart = spart + 500 * P;

  pool_kernel<<<(2 * NWG_PER_TENSOR) / 4, 256, 0, stream>>>(sup, qry, out);
  cos_part<<<BSn * 5, 640, 0, stream>>>(out, dpart, spart, qpart);
  cos_final<<<BSn, 640, 0, stream>>>(dpart, spart, qpart, out);
}